// Round 8
// baseline (226.960 us; speedup 1.0000x reference)
//
#include <hip/hip_runtime.h>
#include <hip/hip_bf16.h>

// MSAPairWeightedAveraging — round 7:
//  k3: LDS-BW-limited diagnosis -> fat wave tiles. Wave = 64n x 128i (acc[4][8]),
//      block = 128n x 256i, BK=64, single-buffer 48 KB, m97 2-barrier loop.
//      Reads/MFMA 0.75 -> 0.375 (2x less LDS read traffic per FLOP).
//      Grid 1024, XCD-chunked: one h per XCD (Wt slice L2-local).
// Shapes: b=1, S=256, N=512, DM=64, DP=128, H=8, C=256. mask all-true.

#define S 256
#define N 512
#define DM 64
#define DP 128
#define H 8
#define C 256
#define ROWS (S * N) // 131072

typedef __attribute__((ext_vector_type(8))) short bf16x8;
typedef __attribute__((ext_vector_type(4))) float f32x4;

static __device__ __forceinline__ float bf2f(unsigned int u16) {
    union { unsigned int i; float f; } x;
    x.i = u16 << 16;
    return x.f;
}
static __device__ __forceinline__ unsigned short f2bf(float f) {
    union { float f; unsigned int i; } x;
    x.f = f;
    unsigned int r = x.i + 0x7FFFu + ((x.i >> 16) & 1u); // RNE
    return (unsigned short)(r >> 16);
}
static __device__ __forceinline__ void gload16(const void* g, void* l) {
    __builtin_amdgcn_global_load_lds(
        (const __attribute__((address_space(1))) void*)g,
        (__attribute__((address_space(3))) void*)l, 16, 0, 0);
}

// ---------------- K0: weight prep ----------------
__global__ __launch_bounds__(256) void k0_prep(
    const float* __restrict__ Wvg, const float* __restrict__ g, const float* __restrict__ b,
    const float* __restrict__ Wout, const float* __restrict__ gp, const float* __restrict__ bp,
    const float* __restrict__ Wp,
    unsigned short* __restrict__ WTvg, float* __restrict__ biasvg, unsigned short* __restrict__ WoutT,
    float* __restrict__ Wg, float* __restrict__ sgcb)
{
    const int t = threadIdx.x;
    if (blockIdx.x < 2) {
        const int c = blockIdx.x * 256 + t;
        float bias = 0.f;
        unsigned short row[64];
#pragma unroll
        for (int k = 0; k < 64; k++) {
            const float w = Wvg[k * 512 + c];
            row[k] = f2bf(w * g[k]);
            bias = fmaf(w, b[k], bias);
        }
#pragma unroll
        for (int q = 0; q < 8; q++) *(uint4*)(WTvg + c * 64 + q * 8) = *(const uint4*)(row + q * 8);
        biasvg[c] = bias;
    } else if (blockIdx.x == 2) {
        const int m = t >> 2, c0 = (t & 3) * 64;
        unsigned short row[64];
#pragma unroll
        for (int q = 0; q < 64; q++) row[q] = f2bf(Wout[(c0 + q) * 64 + m]);
#pragma unroll
        for (int q = 0; q < 8; q++) *(uint4*)(WoutT + m * 256 + c0 + q * 8) = *(const uint4*)(row + q * 8);
    } else {
        if (t < 128) {
            const float gm = gp[t];
#pragma unroll
            for (int h = 0; h < 8; h++) Wg[t * 8 + h] = gm * Wp[t * 8 + h];
        } else if (t < 136) {
            const int h = t - 128;
            float sg = 0.f, cb = 0.f;
            for (int k = 0; k < 128; k++) {
                sg = fmaf(gp[k], Wp[k * 8 + h], sg);
                cb = fmaf(bp[k], Wp[k * 8 + h], cb);
            }
            sgcb[h] = sg;
            sgcb[8 + h] = cb;
        }
    }
}

// ---------------- K1: LN + MFMA -> VT, G ----------------
__global__ __launch_bounds__(512, 4) void k1_vg_mfma(
    const float* __restrict__ msa, const unsigned short* __restrict__ WTvg,
    const float* __restrict__ biasvg,
    unsigned short* __restrict__ VT, unsigned short* __restrict__ G)
{
    __shared__ unsigned short wt[512 * 64]; // 64 KB
    __shared__ unsigned short at[64 * 64];  // 8 KB
    const int t = threadIdx.x, lane = t & 63, w = t >> 6;
    const int l15 = lane & 15, lgrp = lane >> 4;
    const int s = blockIdx.x >> 1;
    const int jbase = (blockIdx.x & 1) * 256;

#pragma unroll
    for (int q = 0; q < 8; q++) {
        const int u = q * 512 + t;
        const int c = u >> 3, ch = u & 7;
        const uint4 v = *(const uint4*)(WTvg + c * 64 + ch * 8);
        *(uint4*)((char*)wt + c * 128 + ((ch ^ (c & 7)) * 16)) = v;
    }
    float biasr[4];
    float bias2[4][4];
    if (w < 4) {
#pragma unroll
        for (int cf = 0; cf < 4; cf++) biasr[cf] = biasvg[w * 64 + cf * 16 + l15];
    } else {
#pragma unroll
        for (int cf = 0; cf < 4; cf++)
#pragma unroll
            for (int r = 0; r < 4; r++) bias2[cf][r] = biasvg[w * 64 + cf * 16 + lgrp * 4 + r];
    }

    for (int tile = 0; tile < 4; ++tile) {
        const int j0 = jbase + tile * 64;
        {
            const int r = t >> 3, kc = (t & 7) * 8;
            const float* src = msa + ((size_t)(s * 512 + j0 + r)) * 64 + kc;
            const float4 x0 = *(const float4*)src;
            const float4 x1 = *(const float4*)(src + 4);
            float s1 = x0.x + x0.y + x0.z + x0.w + x1.x + x1.y + x1.z + x1.w;
            float s2 = x0.x * x0.x + x0.y * x0.y + x0.z * x0.z + x0.w * x0.w
                     + x1.x * x1.x + x1.y * x1.y + x1.z * x1.z + x1.w * x1.w;
#pragma unroll
            for (int off = 1; off < 8; off <<= 1) {
                s1 += __shfl_xor(s1, off);
                s2 += __shfl_xor(s2, off);
            }
            const float m = s1 * (1.f / 64.f);
            const float inv = rsqrtf(s2 * (1.f / 64.f) - m * m + 1e-5f);
            unsigned short buf[8];
            buf[0] = f2bf((x0.x - m) * inv); buf[1] = f2bf((x0.y - m) * inv);
            buf[2] = f2bf((x0.z - m) * inv); buf[3] = f2bf((x0.w - m) * inv);
            buf[4] = f2bf((x1.x - m) * inv); buf[5] = f2bf((x1.y - m) * inv);
            buf[6] = f2bf((x1.z - m) * inv); buf[7] = f2bf((x1.w - m) * inv);
            *(uint4*)((char*)at + r * 128 + (((t & 7) ^ (r & 7)) * 16)) = *(const uint4*)buf;
        }
        __syncthreads();

        f32x4 acc[4][4];
#pragma unroll
        for (int rf = 0; rf < 4; rf++)
#pragma unroll
            for (int cf = 0; cf < 4; cf++) acc[rf][cf] = (f32x4){0.f, 0.f, 0.f, 0.f};

#pragma unroll
        for (int ks = 0; ks < 2; ks++) {
            bf16x8 bfr[4];
#pragma unroll
            for (int cf = 0; cf < 4; cf++) {
                const int c = w * 64 + cf * 16 + l15;
                bfr[cf] = *(const bf16x8*)((const char*)wt + c * 128 + (((ks * 4 + lgrp) ^ (c & 7)) * 16));
            }
#pragma unroll
            for (int rf = 0; rf < 4; rf++) {
                const int rr = rf * 16 + l15;
                const bf16x8 afr = *(const bf16x8*)((const char*)at + rr * 128 + (((ks * 4 + lgrp) ^ (rr & 7)) * 16));
                if (w < 4) {
#pragma unroll
                    for (int cf = 0; cf < 4; cf++)
                        acc[rf][cf] = __builtin_amdgcn_mfma_f32_16x16x32_bf16(afr, bfr[cf], acc[rf][cf], 0, 0, 0);
                } else {
#pragma unroll
                    for (int cf = 0; cf < 4; cf++)
                        acc[rf][cf] = __builtin_amdgcn_mfma_f32_16x16x32_bf16(bfr[cf], afr, acc[rf][cf], 0, 0, 0);
                }
            }
        }
        __syncthreads();

        if (w < 4) {
#pragma unroll
            for (int rf = 0; rf < 4; rf++)
#pragma unroll
                for (int cf = 0; cf < 4; cf++) {
                    const int c = w * 64 + cf * 16 + l15;
                    const int j = j0 + rf * 16 + lgrp * 4;
                    uint2 o;
                    o.x = (unsigned)f2bf(acc[rf][cf][0] + biasr[cf]) |
                          ((unsigned)f2bf(acc[rf][cf][1] + biasr[cf]) << 16);
                    o.y = (unsigned)f2bf(acc[rf][cf][2] + biasr[cf]) |
                          ((unsigned)f2bf(acc[rf][cf][3] + biasr[cf]) << 16);
                    *(uint2*)(VT + ((size_t)s * C + c) * N + j) = o;
                }
        } else {
#pragma unroll
            for (int rf = 0; rf < 4; rf++)
#pragma unroll
                for (int cf = 0; cf < 4; cf++) {
                    const int j = j0 + rf * 16 + l15;
                    const int cp = (w - 4) * 64 + cf * 16 + lgrp * 4;
                    float sg[4];
#pragma unroll
                    for (int r = 0; r < 4; r++)
                        sg[r] = 1.f / (1.f + __expf(-(acc[rf][cf][r] + bias2[cf][r])));
                    uint2 o;
                    o.x = (unsigned)f2bf(sg[0]) | ((unsigned)f2bf(sg[1]) << 16);
                    o.y = (unsigned)f2bf(sg[2]) | ((unsigned)f2bf(sg[3]) << 16);
                    *(uint2*)(G + ((size_t)(s * 512 + j)) * C + cp) = o;
                }
        }
    }
}

// ---------------- K2: pair bias + softmax (row-group parallel) ----------------
__global__ __launch_bounds__(512) void k2_bias_softmax(
    const float* __restrict__ pair, const float* __restrict__ Wg,
    const float* __restrict__ sgcb, unsigned short* __restrict__ Wt)
{
    __shared__ float bias_lds[H][N]; // 16 KB
    const int i = blockIdx.x;
    const int t = threadIdx.x;
    const int sub = t & 15, rgrp = t >> 4;

    float wreg[2][4][8];
#pragma unroll
    for (int q = 0; q < 2; q++)
#pragma unroll
        for (int c = 0; c < 4; c++) {
            const int k = (q * 16 + sub) * 4 + c;
            const float4 w0 = *(const float4*)(Wg + k * 8);
            const float4 w1 = *(const float4*)(Wg + k * 8 + 4);
            wreg[q][c][0] = w0.x; wreg[q][c][1] = w0.y; wreg[q][c][2] = w0.z; wreg[q][c][3] = w0.w;
            wreg[q][c][4] = w1.x; wreg[q][c][5] = w1.y; wreg[q][c][6] = w1.z; wreg[q][c][7] = w1.w;
        }
    float sgr[8], cbr[8];
#pragma unroll
    for (int h = 0; h < 8; h++) { sgr[h] = sgcb[h]; cbr[h] = sgcb[8 + h]; }

    for (int pass = 0; pass < 16; ++pass) {
        const int r = pass * 32 + rgrp;
        const float* px = pair + ((size_t)i * N + r) * DP;
        const float4 x0 = *(const float4*)(px + (0 * 16 + sub) * 4);
        const float4 x1 = *(const float4*)(px + (1 * 16 + sub) * 4);
        float s1 = x0.x + x0.y + x0.z + x0.w + x1.x + x1.y + x1.z + x1.w;
        float s2 = x0.x * x0.x + x0.y * x0.y + x0.z * x0.z + x0.w * x0.w
                 + x1.x * x1.x + x1.y * x1.y + x1.z * x1.z + x1.w * x1.w;
#pragma unroll
        for (int off = 1; off < 16; off <<= 1) {
            s1 += __shfl_xor(s1, off);
            s2 += __shfl_xor(s2, off);
        }
        const float m = s1 * (1.f / 128.f);
        const float inv = rsqrtf(s2 * (1.f / 128.f) - m * m + 1e-5f);

        float dots[8];
#pragma unroll
        for (int h = 0; h < 8; h++) dots[h] = 0.f;
        const float xs[2][4] = {{x0.x, x0.y, x0.z, x0.w}, {x1.x, x1.y, x1.z, x1.w}};
#pragma unroll
        for (int q = 0; q < 2; q++)
#pragma unroll
            for (int c = 0; c < 4; c++)
#pragma unroll
                for (int h = 0; h < 8; h++) dots[h] = fmaf(xs[q][c], wreg[q][c][h], dots[h]);
#pragma unroll
        for (int off = 1; off < 16; off <<= 1)
#pragma unroll
            for (int h = 0; h < 8; h++) dots[h] += __shfl_xor(dots[h], off);

        if (sub == 0) {
#pragma unroll
            for (int h = 0; h < 8; h++)
                bias_lds[h][r] = inv * (dots[h] - m * sgr[h]) + cbr[h];
        }
    }
    __syncthreads();

    const int lane = t & 63, h = t >> 6;
    float v[8];
    float mx = -1e30f;
#pragma unroll
    for (int q = 0; q < 8; q++) {
        v[q] = bias_lds[h][q * 64 + lane];
        mx = fmaxf(mx, v[q]);
    }
#pragma unroll
    for (int off = 32; off > 0; off >>= 1) mx = fmaxf(mx, __shfl_xor(mx, off));
    float sum = 0.f;
#pragma unroll
    for (int q = 0; q < 8; q++) {
        v[q] = __expf(v[q] - mx);
        sum += v[q];
    }
#pragma unroll
    for (int off = 32; off > 0; off >>= 1) sum += __shfl_xor(sum, off);
    const float rs = 1.f / sum;
#pragma unroll
    for (int q = 0; q < 8; q++)
        Wt[((size_t)h * N + i) * N + q * 64 + lane] = f2bf(v[q] * rs);
}

// ---------------- K3: per-h GEMM, fat wave tiles (LDS-BW fix) ----------------
// grid 1024 = 8h x 64 n-tiles(128) x 2 i-tiles(256); 4 waves = 2x2 of 64n x 128i.
// acc[4][8] per thread; 0.375 ds_reads/MFMA. Single-buffer 48 KB LDS, 2-barrier loop.
// XCD-chunked so each XCD owns one h (Wt[h] slice stays L2-local).
__global__ __launch_bounds__(256, 2) void k3_einsum_h(
    const unsigned short* __restrict__ Wt, const unsigned short* __restrict__ VT,
    unsigned short* __restrict__ G)
{
    __shared__ unsigned short a_lds[128 * 64]; // 16 KB
    __shared__ unsigned short b_lds[256 * 64]; // 32 KB
    const int raw = blockIdx.x;
    const int bid = (raw & 7) * 128 + (raw >> 3); // 1024 % 8 == 0
    const int h = bid >> 7;
    const int rem = bid & 127;
    const int nb = rem >> 1, ib = rem & 1;
    const int n0 = nb * 128, i0 = ib * 256;
    const int t = threadIdx.x, lane = t & 63, w = t >> 6;
    const int l15 = lane & 15, lgrp = lane >> 4;
    const int wn = w >> 1, wi = w & 1;

    // staging bases (source pre-swizzled, LDS dest linear)
    const unsigned short* srcA[4];
    const unsigned short* srcB[8];
    int dstA[4], dstB[8];
#pragma unroll
    for (int q = 0; q < 4; ++q) {
        const int slot = q * 256 + t;           // 0..1023 (A: 128 rows x 8 chunks)
        const int row = slot >> 3, chp = slot & 7;
        const int ch = chp ^ (row & 7);
        const int n = n0 + row;
        srcA[q] = VT + ((size_t)((n >> 5) * 256 + h * 32 + (n & 31))) * 512 + ch * 8;
        dstA[q] = slot * 16;
    }
#pragma unroll
    for (int q = 0; q < 8; ++q) {
        const int slot = q * 256 + t;           // 0..2047 (B: 256 rows x 8 chunks)
        const int row = slot >> 3, chp = slot & 7;
        const int ch = chp ^ (row & 7);
        srcB[q] = Wt + ((size_t)(h * 512 + i0 + row)) * 512 + ch * 8;
        dstB[q] = slot * 16;
    }

    f32x4 acc[4][8];
#pragma unroll
    for (int fn = 0; fn < 4; fn++)
#pragma unroll
        for (int fi = 0; fi < 8; fi++) acc[fn][fi] = (f32x4){0.f, 0.f, 0.f, 0.f};

    for (int kt = 0; kt < 8; ++kt) {
        const int j0 = kt * 64;
#pragma unroll
        for (int q = 0; q < 4; ++q) gload16(srcA[q] + j0, (char*)a_lds + dstA[q]);
#pragma unroll
        for (int q = 0; q < 8; ++q) gload16(srcB[q] + j0, (char*)b_lds + dstB[q]);
        __syncthreads(); // drains vmcnt -> staged data visible

#pragma unroll
        for (int ks = 0; ks < 2; ++ks) {
            bf16x8 af[4];
#pragma unroll
            for (int fn = 0; fn < 4; ++fn) {
                const int ra = wn * 64 + fn * 16 + l15;
                af[fn] = *(const bf16x8*)((const char*)a_lds + ra * 128 + (((ks * 4 + lgrp) ^ (ra & 7)) * 16));
            }
            bf16x8 bf[8];
#pragma unroll
            for (int fi = 0; fi < 8; ++fi) {
                const int rb = wi * 128 + fi * 16 + l15;
                bf[fi] = *(const bf16x8*)((const char*)b_lds + rb * 128 + (((ks * 4 + lgrp) ^ (rb & 7)) * 16));
            }
#pragma unroll
            for (int fn = 0; fn < 4; ++fn)
#pragma unroll
                for (int fi = 0; fi < 8; ++fi)
                    acc[fn][fi] = __builtin_amdgcn_mfma_f32_16x16x32_bf16(af[fn], bf[fi], acc[fn][fi], 0, 0, 0);
        }
        __syncthreads(); // compute done before next stage overwrites
    }

    // epilogue: gated = D * G (in place, uint2 RMW)
#pragma unroll
    for (int fn = 0; fn < 4; ++fn) {
        const int nl = n0 + wn * 64 + fn * 16 + lgrp * 4;
        const int s = nl >> 5, d = nl & 31;
#pragma unroll
        for (int fi = 0; fi < 8; ++fi) {
            const int i = i0 + wi * 128 + fi * 16 + l15;
            const size_t base = ((size_t)(s * 512 + i)) * 256 + h * 32 + d;
            const uint2 uu = *(const uint2*)(G + base);
            const float g0 = bf2f(uu.x & 0xFFFFu), g1 = bf2f(uu.x >> 16);
            const float g2 = bf2f(uu.y & 0xFFFFu), g3 = bf2f(uu.y >> 16);
            uint2 o;
            o.x = (unsigned)f2bf(acc[fn][fi][0] * g0) | ((unsigned)f2bf(acc[fn][fi][1] * g1) << 16);
            o.y = (unsigned)f2bf(acc[fn][fi][2] * g2) | ((unsigned)f2bf(acc[fn][fi][3] * g3) << 16);
            *(uint2*)(G + base) = o;
        }
    }
}

// ---------------- K4: out = gated @ WoutT (MFMA, K=256 fits in LDS) ----------------
__global__ __launch_bounds__(256, 4) void k4_out(
    const unsigned short* __restrict__ gated, const unsigned short* __restrict__ WoutT,
    float* __restrict__ out)
{
    __shared__ unsigned short w_lds[64 * 256]; // 32 KB
    __shared__ unsigned short a_lds[64 * 256]; // 32 KB
    const int t = threadIdx.x, lane = t & 63, w = t >> 6;
    const int l15 = lane & 15, lgrp = lane >> 4;
    const size_t r0 = (size_t)blockIdx.x * 64;

#pragma unroll
    for (int q = 0; q < 8; ++q) {
        const int u = q * 256 + t;
        const int row = u >> 5, kc = u & 31;
        const uint4 v = *(const uint4*)(WoutT + row * 256 + kc * 8);
        *(uint4*)((char*)w_lds + row * 512 + ((kc ^ (row & 31)) * 16)) = v;
    }
#pragma unroll
    for (int q = 0; q < 8; ++q) {
        const int slot = q * 256 + t;
        const int row = slot >> 5, chp = slot & 31;
        const int ch = chp ^ (row & 31);
        gload16(gated + (r0 + row) * 256 + ch * 8,
                (char*)a_lds + (q * 256 + (t & 192)) * 16);
    }
    __syncthreads();

    f32x4 acc[4];
#pragma unroll
    for (int fm = 0; fm < 4; fm++) acc[fm] = (f32x4){0.f, 0.f, 0.f, 0.f};
#pragma unroll
    for (int ks = 0; ks < 8; ++ks) {
        const int ra = w * 16 + l15;
        const bf16x8 af = *(const bf16x8*)((const char*)a_lds + ra * 512 + (((ks * 4 + lgrp) ^ (ra & 31)) * 16));
#pragma unroll
        for (int fm = 0; fm < 4; ++fm) {
            const int rm = fm * 16 + l15;
            const bf16x8 bf = *(const bf16x8*)((const char*)w_lds + rm * 512 + (((ks * 4 + lgrp) ^ (rm & 31)) * 16));
            acc[fm] = __builtin_amdgcn_mfma_f32_16x16x32_bf16(af, bf, acc[fm], 0, 0, 0);
        }
    }
#pragma unroll
    for (int fm = 0; fm < 4; ++fm)
#pragma unroll
        for (int r = 0; r < 4; ++r)
            out[(r0 + w * 16 + lgrp * 4 + r) * 64 + fm * 16 + l15] = acc[fm][r];
}

extern "C" void kernel_launch(void* const* d_in, const int* in_sizes, int n_in,
                              void* d_out, int out_size, void* d_ws, size_t ws_size,
                              hipStream_t stream) {
    (void)in_sizes; (void)n_in; (void)out_size; (void)ws_size;
    const float* msa       = (const float*)d_in[0];
    const float* pair      = (const float*)d_in[1];
    const float* ln_msa_g  = (const float*)d_in[2];
    const float* ln_msa_b  = (const float*)d_in[3];
    const float* W_vg      = (const float*)d_in[4];
    const float* ln_pair_g = (const float*)d_in[5];
    const float* ln_pair_b = (const float*)d_in[6];
    const float* W_pair    = (const float*)d_in[7];
    const float* W_out     = (const float*)d_in[8];
    float* out = (float*)d_out;

    char* ws = (char*)d_ws;
    size_t off = 0;
    unsigned short* VT    = (unsigned short*)(ws + off); off += (size_t)ROWS * C * 2; // 67.1 MB
    unsigned short* G     = (unsigned short*)(ws + off); off += (size_t)ROWS * C * 2; // 67.1 MB
    unsigned short* Wt    = (unsigned short*)(ws + off); off += (size_t)H * N * N * 2; // 4.2 MB
    unsigned short* WTvg  = (unsigned short*)(ws + off); off += 512 * 64 * 2;          // 64 KB
    float*          biasvg = (float*)(ws + off); off += 512 * 4;                       // 2 KB
    unsigned short* WoutT = (unsigned short*)(ws + off); off += 64 * 256 * 2;          // 32 KB
    float*          Wg    = (float*)(ws + off); off += 128 * 8 * 4;                    // 4 KB
    float*          sgcb  = (float*)(ws + off); off += 16 * 4;

    k0_prep<<<4, 256, 0, stream>>>(W_vg, ln_msa_g, ln_msa_b, W_out, ln_pair_g, ln_pair_b, W_pair,
                                   WTvg, biasvg, WoutT, Wg, sgcb);
    k2_bias_softmax<<<512, 512, 0, stream>>>(pair, Wg, sgcb, Wt);
    k1_vg_mfma<<<512, 512, 0, stream>>>(msa, WTvg, biasvg, VT, G);
    k3_einsum_h<<<1024, 256, 0, stream>>>(Wt, VT, G);
    k4_out<<<2048, 256, 0, stream>>>(G, WoutT, out);
}

// Round 9
// 203.455 us; speedup vs baseline: 1.1155x; 1.1155x over previous
//
#include <hip/hip_runtime.h>
#include <hip/hip_bf16.h>

// MSAPairWeightedAveraging — round 8: k4 fused INTO k3 (gate + W_out as per-h
// mini-GEMM epilogue). k3's pipes were all <20% busy across 4 schedule variants
// (stuck at 85us) -> add work there, delete k4 + G-write + gated re-read.
// Shapes: b=1, S=256, N=512, DM=64, DP=128, H=8, C=256. mask all-true.
//
//  K0: prep: WTvg, biasvg, WoutT[m][c], Wg, sgcb
//  K1: LN(msa) -> MFMA -> VT[s][c][j] bf16, G[s][j][c]=sigmoid bf16 (read-only after)
//  K2: pair bias + softmax -> Wt[h][i][j] bf16
//  K3: per (s-pair, i-tile): loop h { GEMM1 (K=512) -> gate (G prefetched) ->
//      mini-GEMM @ WoutT h-slice accumulating out[s][i][m] } -> fp32 out write.

#define S 256
#define N 512
#define DM 64
#define DP 128
#define H 8
#define C 256
#define ROWS (S * N) // 131072

typedef __attribute__((ext_vector_type(8))) short bf16x8;
typedef __attribute__((ext_vector_type(4))) float f32x4;

static __device__ __forceinline__ float bf2f(unsigned int u16) {
    union { unsigned int i; float f; } x;
    x.i = u16 << 16;
    return x.f;
}
static __device__ __forceinline__ unsigned short f2bf(float f) {
    union { float f; unsigned int i; } x;
    x.f = f;
    unsigned int r = x.i + 0x7FFFu + ((x.i >> 16) & 1u); // RNE
    return (unsigned short)(r >> 16);
}
static __device__ __forceinline__ void gload16(const void* g, void* l) {
    __builtin_amdgcn_global_load_lds(
        (const __attribute__((address_space(1))) void*)g,
        (__attribute__((address_space(3))) void*)l, 16, 0, 0);
}

// ---------------- K0: weight prep ----------------
__global__ __launch_bounds__(256) void k0_prep(
    const float* __restrict__ Wvg, const float* __restrict__ g, const float* __restrict__ b,
    const float* __restrict__ Wout, const float* __restrict__ gp, const float* __restrict__ bp,
    const float* __restrict__ Wp,
    unsigned short* __restrict__ WTvg, float* __restrict__ biasvg, unsigned short* __restrict__ WoutT,
    float* __restrict__ Wg, float* __restrict__ sgcb)
{
    const int t = threadIdx.x;
    if (blockIdx.x < 2) {
        const int c = blockIdx.x * 256 + t;
        float bias = 0.f;
        unsigned short row[64];
#pragma unroll
        for (int k = 0; k < 64; k++) {
            const float w = Wvg[k * 512 + c];
            row[k] = f2bf(w * g[k]);
            bias = fmaf(w, b[k], bias);
        }
#pragma unroll
        for (int q = 0; q < 8; q++) *(uint4*)(WTvg + c * 64 + q * 8) = *(const uint4*)(row + q * 8);
        biasvg[c] = bias;
    } else if (blockIdx.x == 2) {
        const int m = t >> 2, c0 = (t & 3) * 64;
        unsigned short row[64];
#pragma unroll
        for (int q = 0; q < 64; q++) row[q] = f2bf(Wout[(c0 + q) * 64 + m]);
#pragma unroll
        for (int q = 0; q < 8; q++) *(uint4*)(WoutT + m * 256 + c0 + q * 8) = *(const uint4*)(row + q * 8);
    } else {
        if (t < 128) {
            const float gm = gp[t];
#pragma unroll
            for (int h = 0; h < 8; h++) Wg[t * 8 + h] = gm * Wp[t * 8 + h];
        } else if (t < 136) {
            const int h = t - 128;
            float sg = 0.f, cb = 0.f;
            for (int k = 0; k < 128; k++) {
                sg = fmaf(gp[k], Wp[k * 8 + h], sg);
                cb = fmaf(bp[k], Wp[k * 8 + h], cb);
            }
            sgcb[h] = sg;
            sgcb[8 + h] = cb;
        }
    }
}

// ---------------- K1: LN + MFMA -> VT, G ----------------
__global__ __launch_bounds__(512, 4) void k1_vg_mfma(
    const float* __restrict__ msa, const unsigned short* __restrict__ WTvg,
    const float* __restrict__ biasvg,
    unsigned short* __restrict__ VT, unsigned short* __restrict__ G)
{
    __shared__ unsigned short wt[512 * 64]; // 64 KB
    __shared__ unsigned short at[64 * 64];  // 8 KB
    const int t = threadIdx.x, lane = t & 63, w = t >> 6;
    const int l15 = lane & 15, lgrp = lane >> 4;
    const int s = blockIdx.x >> 1;
    const int jbase = (blockIdx.x & 1) * 256;

#pragma unroll
    for (int q = 0; q < 8; q++) {
        const int u = q * 512 + t;
        const int c = u >> 3, ch = u & 7;
        const uint4 v = *(const uint4*)(WTvg + c * 64 + ch * 8);
        *(uint4*)((char*)wt + c * 128 + ((ch ^ (c & 7)) * 16)) = v;
    }
    float biasr[4];
    float bias2[4][4];
    if (w < 4) {
#pragma unroll
        for (int cf = 0; cf < 4; cf++) biasr[cf] = biasvg[w * 64 + cf * 16 + l15];
    } else {
#pragma unroll
        for (int cf = 0; cf < 4; cf++)
#pragma unroll
            for (int r = 0; r < 4; r++) bias2[cf][r] = biasvg[w * 64 + cf * 16 + lgrp * 4 + r];
    }

    for (int tile = 0; tile < 4; ++tile) {
        const int j0 = jbase + tile * 64;
        {
            const int r = t >> 3, kc = (t & 7) * 8;
            const float* src = msa + ((size_t)(s * 512 + j0 + r)) * 64 + kc;
            const float4 x0 = *(const float4*)src;
            const float4 x1 = *(const float4*)(src + 4);
            float s1 = x0.x + x0.y + x0.z + x0.w + x1.x + x1.y + x1.z + x1.w;
            float s2 = x0.x * x0.x + x0.y * x0.y + x0.z * x0.z + x0.w * x0.w
                     + x1.x * x1.x + x1.y * x1.y + x1.z * x1.z + x1.w * x1.w;
#pragma unroll
            for (int off = 1; off < 8; off <<= 1) {
                s1 += __shfl_xor(s1, off);
                s2 += __shfl_xor(s2, off);
            }
            const float m = s1 * (1.f / 64.f);
            const float inv = rsqrtf(s2 * (1.f / 64.f) - m * m + 1e-5f);
            unsigned short buf[8];
            buf[0] = f2bf((x0.x - m) * inv); buf[1] = f2bf((x0.y - m) * inv);
            buf[2] = f2bf((x0.z - m) * inv); buf[3] = f2bf((x0.w - m) * inv);
            buf[4] = f2bf((x1.x - m) * inv); buf[5] = f2bf((x1.y - m) * inv);
            buf[6] = f2bf((x1.z - m) * inv); buf[7] = f2bf((x1.w - m) * inv);
            *(uint4*)((char*)at + r * 128 + (((t & 7) ^ (r & 7)) * 16)) = *(const uint4*)buf;
        }
        __syncthreads();

        f32x4 acc[4][4];
#pragma unroll
        for (int rf = 0; rf < 4; rf++)
#pragma unroll
            for (int cf = 0; cf < 4; cf++) acc[rf][cf] = (f32x4){0.f, 0.f, 0.f, 0.f};

#pragma unroll
        for (int ks = 0; ks < 2; ks++) {
            bf16x8 bfr[4];
#pragma unroll
            for (int cf = 0; cf < 4; cf++) {
                const int c = w * 64 + cf * 16 + l15;
                bfr[cf] = *(const bf16x8*)((const char*)wt + c * 128 + (((ks * 4 + lgrp) ^ (c & 7)) * 16));
            }
#pragma unroll
            for (int rf = 0; rf < 4; rf++) {
                const int rr = rf * 16 + l15;
                const bf16x8 afr = *(const bf16x8*)((const char*)at + rr * 128 + (((ks * 4 + lgrp) ^ (rr & 7)) * 16));
                if (w < 4) {
#pragma unroll
                    for (int cf = 0; cf < 4; cf++)
                        acc[rf][cf] = __builtin_amdgcn_mfma_f32_16x16x32_bf16(afr, bfr[cf], acc[rf][cf], 0, 0, 0);
                } else {
#pragma unroll
                    for (int cf = 0; cf < 4; cf++)
                        acc[rf][cf] = __builtin_amdgcn_mfma_f32_16x16x32_bf16(bfr[cf], afr, acc[rf][cf], 0, 0, 0);
                }
            }
        }
        __syncthreads();

        if (w < 4) {
#pragma unroll
            for (int rf = 0; rf < 4; rf++)
#pragma unroll
                for (int cf = 0; cf < 4; cf++) {
                    const int c = w * 64 + cf * 16 + l15;
                    const int j = j0 + rf * 16 + lgrp * 4;
                    uint2 o;
                    o.x = (unsigned)f2bf(acc[rf][cf][0] + biasr[cf]) |
                          ((unsigned)f2bf(acc[rf][cf][1] + biasr[cf]) << 16);
                    o.y = (unsigned)f2bf(acc[rf][cf][2] + biasr[cf]) |
                          ((unsigned)f2bf(acc[rf][cf][3] + biasr[cf]) << 16);
                    *(uint2*)(VT + ((size_t)s * C + c) * N + j) = o;
                }
        } else {
#pragma unroll
            for (int rf = 0; rf < 4; rf++)
#pragma unroll
                for (int cf = 0; cf < 4; cf++) {
                    const int j = j0 + rf * 16 + l15;
                    const int cp = (w - 4) * 64 + cf * 16 + lgrp * 4;
                    float sg[4];
#pragma unroll
                    for (int r = 0; r < 4; r++)
                        sg[r] = 1.f / (1.f + __expf(-(acc[rf][cf][r] + bias2[cf][r])));
                    uint2 o;
                    o.x = (unsigned)f2bf(sg[0]) | ((unsigned)f2bf(sg[1]) << 16);
                    o.y = (unsigned)f2bf(sg[2]) | ((unsigned)f2bf(sg[3]) << 16);
                    *(uint2*)(G + ((size_t)(s * 512 + j)) * C + cp) = o;
                }
        }
    }
}

// ---------------- K2: pair bias + softmax (row-group parallel) ----------------
__global__ __launch_bounds__(512) void k2_bias_softmax(
    const float* __restrict__ pair, const float* __restrict__ Wg,
    const float* __restrict__ sgcb, unsigned short* __restrict__ Wt)
{
    __shared__ float bias_lds[H][N]; // 16 KB
    const int i = blockIdx.x;
    const int t = threadIdx.x;
    const int sub = t & 15, rgrp = t >> 4;

    float wreg[2][4][8];
#pragma unroll
    for (int q = 0; q < 2; q++)
#pragma unroll
        for (int c = 0; c < 4; c++) {
            const int k = (q * 16 + sub) * 4 + c;
            const float4 w0 = *(const float4*)(Wg + k * 8);
            const float4 w1 = *(const float4*)(Wg + k * 8 + 4);
            wreg[q][c][0] = w0.x; wreg[q][c][1] = w0.y; wreg[q][c][2] = w0.z; wreg[q][c][3] = w0.w;
            wreg[q][c][4] = w1.x; wreg[q][c][5] = w1.y; wreg[q][c][6] = w1.z; wreg[q][c][7] = w1.w;
        }
    float sgr[8], cbr[8];
#pragma unroll
    for (int h = 0; h < 8; h++) { sgr[h] = sgcb[h]; cbr[h] = sgcb[8 + h]; }

    for (int pass = 0; pass < 16; ++pass) {
        const int r = pass * 32 + rgrp;
        const float* px = pair + ((size_t)i * N + r) * DP;
        const float4 x0 = *(const float4*)(px + (0 * 16 + sub) * 4);
        const float4 x1 = *(const float4*)(px + (1 * 16 + sub) * 4);
        float s1 = x0.x + x0.y + x0.z + x0.w + x1.x + x1.y + x1.z + x1.w;
        float s2 = x0.x * x0.x + x0.y * x0.y + x0.z * x0.z + x0.w * x0.w
                 + x1.x * x1.x + x1.y * x1.y + x1.z * x1.z + x1.w * x1.w;
#pragma unroll
        for (int off = 1; off < 16; off <<= 1) {
            s1 += __shfl_xor(s1, off);
            s2 += __shfl_xor(s2, off);
        }
        const float m = s1 * (1.f / 128.f);
        const float inv = rsqrtf(s2 * (1.f / 128.f) - m * m + 1e-5f);

        float dots[8];
#pragma unroll
        for (int h = 0; h < 8; h++) dots[h] = 0.f;
        const float xs[2][4] = {{x0.x, x0.y, x0.z, x0.w}, {x1.x, x1.y, x1.z, x1.w}};
#pragma unroll
        for (int q = 0; q < 2; q++)
#pragma unroll
            for (int c = 0; c < 4; c++)
#pragma unroll
                for (int h = 0; h < 8; h++) dots[h] = fmaf(xs[q][c], wreg[q][c][h], dots[h]);
#pragma unroll
        for (int off = 1; off < 16; off <<= 1)
#pragma unroll
            for (int h = 0; h < 8; h++) dots[h] += __shfl_xor(dots[h], off);

        if (sub == 0) {
#pragma unroll
            for (int h = 0; h < 8; h++)
                bias_lds[h][r] = inv * (dots[h] - m * sgr[h]) + cbr[h];
        }
    }
    __syncthreads();

    const int lane = t & 63, h = t >> 6;
    float v[8];
    float mx = -1e30f;
#pragma unroll
    for (int q = 0; q < 8; q++) {
        v[q] = bias_lds[h][q * 64 + lane];
        mx = fmaxf(mx, v[q]);
    }
#pragma unroll
    for (int off = 32; off > 0; off >>= 1) mx = fmaxf(mx, __shfl_xor(mx, off));
    float sum = 0.f;
#pragma unroll
    for (int q = 0; q < 8; q++) {
        v[q] = __expf(v[q] - mx);
        sum += v[q];
    }
#pragma unroll
    for (int off = 32; off > 0; off >>= 1) sum += __shfl_xor(sum, off);
    const float rs = 1.f / sum;
#pragma unroll
    for (int q = 0; q < 8; q++)
        Wt[((size_t)h * N + i) * N + q * 64 + lane] = f2bf(v[q] * rs);
}

// ---------------- K3: fused einsum + gate + W_out ----------------
// Block = (s-pair, 128-i tile); grid 512 = 128 sp x 4 it (XCD-chunked: the 4
// it-blocks of an sp are consecutive within one XCD -> VT slab L2-shared).
// 4 waves 2x2: wave (wn, wi) = 32n x 64i per h; acc[2][4]; oacc[2 s][2 if][4 mf].
// Per h: prefetch gates -> 8-step j-loop (2-barrier) -> gate into g_lds ->
// mini-GEMM (A=gated i-rows from LDS, B=WoutT m-rows from global/L1) -> oacc.
__global__ __launch_bounds__(256, 2) void k3_fused_out(
    const unsigned short* __restrict__ Wt, const unsigned short* __restrict__ VT,
    const unsigned short* __restrict__ G, const unsigned short* __restrict__ WoutT,
    float* __restrict__ out)
{
    __shared__ unsigned short a_lds[64 * 64];       // 8 KB  [64 n][64 j] swz8
    __shared__ unsigned short b_lds[128 * 64];      // 16 KB [128 i][64 j] swz8
    __shared__ unsigned short g_lds[2 * 128 * 32];  // 16 KB [s][128 i][32 d] swz4
    const int raw = blockIdx.x;
    const int bid = (raw & 7) * 64 + (raw >> 3);    // 512 % 8 == 0
    const int sp = bid >> 2;
    const int it = bid & 3;
    const int s0 = sp * 2, i0 = it * 128;
    const int t = threadIdx.x, lane = t & 63, w = t >> 6;
    const int l15 = lane & 15, lgrp = lane >> 4;
    const int wn = w >> 1, wi = w & 1;

    // staging bases (source pre-swizzled, LDS dest linear)
    const unsigned short* srcA[2];
    const unsigned short* srcB[4];
    int dstA[2], dstB[4];
#pragma unroll
    for (int q = 0; q < 2; ++q) {
        const int slot = q * 256 + t;               // 0..511: A 64 rows x 8 chunks
        const int row = slot >> 3, chp = slot & 7;
        const int ch = chp ^ (row & 7);
        srcA[q] = VT + ((size_t)((s0 + (row >> 5)) * 256 + (row & 31))) * 512 + ch * 8;
        dstA[q] = slot * 16;
    }
#pragma unroll
    for (int q = 0; q < 4; ++q) {
        const int slot = q * 256 + t;               // 0..1023: B 128 rows x 8 chunks
        const int row = slot >> 3, chp = slot & 7;
        const int ch = chp ^ (row & 7);
        srcB[q] = Wt + ((size_t)(i0 + row)) * 512 + ch * 8;
        dstB[q] = slot * 16;
    }

    f32x4 oacc[2][2][4]; // [s][if][mf]
#pragma unroll
    for (int s = 0; s < 2; s++)
#pragma unroll
        for (int f = 0; f < 2; f++)
#pragma unroll
            for (int mf = 0; mf < 4; mf++) oacc[s][f][mf] = (f32x4){0.f, 0.f, 0.f, 0.f};

    for (int h = 0; h < 8; ++h) {
        // prefetch this h's gates (consumed after the j-loop; latency hidden)
        uint2 gpre[2][4];
#pragma unroll
        for (int fn = 0; fn < 2; ++fn)
#pragma unroll
            for (int fi = 0; fi < 4; ++fi)
                gpre[fn][fi] = *(const uint2*)(G +
                    ((size_t)((s0 + wn) * 512 + i0 + wi * 64 + fi * 16 + l15)) * 256 +
                    h * 32 + fn * 16 + lgrp * 4);

        f32x4 acc[2][4];
#pragma unroll
        for (int fn = 0; fn < 2; fn++)
#pragma unroll
            for (int fi = 0; fi < 4; fi++) acc[fn][fi] = (f32x4){0.f, 0.f, 0.f, 0.f};

        const int offA = h * 16384; // h*32*512
        const int offB = h * 262144; // h*512*512
        for (int kt = 0; kt < 8; ++kt) {
            const int j0 = kt * 64;
#pragma unroll
            for (int q = 0; q < 2; ++q) gload16(srcA[q] + offA + j0, (char*)a_lds + dstA[q]);
#pragma unroll
            for (int q = 0; q < 4; ++q) gload16(srcB[q] + offB + j0, (char*)b_lds + dstB[q]);
            __syncthreads();
#pragma unroll
            for (int ks = 0; ks < 2; ++ks) {
                bf16x8 af[2], bf[4];
#pragma unroll
                for (int fn = 0; fn < 2; ++fn) {
                    const int ra = wn * 32 + fn * 16 + l15;
                    af[fn] = *(const bf16x8*)((const char*)a_lds + ra * 128 + (((ks * 4 + lgrp) ^ (ra & 7)) * 16));
                }
#pragma unroll
                for (int fi = 0; fi < 4; ++fi) {
                    const int rb = wi * 64 + fi * 16 + l15;
                    bf[fi] = *(const bf16x8*)((const char*)b_lds + rb * 128 + (((ks * 4 + lgrp) ^ (rb & 7)) * 16));
                }
#pragma unroll
                for (int fn = 0; fn < 2; ++fn)
#pragma unroll
                    for (int fi = 0; fi < 4; ++fi)
                        acc[fn][fi] = __builtin_amdgcn_mfma_f32_16x16x32_bf16(af[fn], bf[fi], acc[fn][fi], 0, 0, 0);
            }
            __syncthreads();
        }

        // gate + pack -> g_lds[s=wn][i][d] (4-chunk swizzle)
#pragma unroll
        for (int fn = 0; fn < 2; ++fn) {
            const int d0 = fn * 16 + lgrp * 4;
#pragma unroll
            for (int fi = 0; fi < 4; ++fi) {
                const int i = wi * 64 + fi * 16 + l15;
                const uint2 uu = gpre[fn][fi];
                const float g0 = bf2f(uu.x & 0xFFFFu), g1 = bf2f(uu.x >> 16);
                const float g2 = bf2f(uu.y & 0xFFFFu), g3 = bf2f(uu.y >> 16);
                uint2 o;
                o.x = (unsigned)f2bf(acc[fn][fi][0] * g0) | ((unsigned)f2bf(acc[fn][fi][1] * g1) << 16);
                o.y = (unsigned)f2bf(acc[fn][fi][2] * g2) | ((unsigned)f2bf(acc[fn][fi][3] * g3) << 16);
                *(uint2*)((char*)g_lds + wn * 8192 + i * 64 + (((d0 >> 3) ^ (i & 3)) * 16) + (d0 & 7) * 2) = o;
            }
        }
        __syncthreads();

        // mini-GEMM: oacc[s][if][mf] += gated[s] @ WoutT(h-slice)
        bf16x8 bw[4];
#pragma unroll
        for (int mf = 0; mf < 4; ++mf)
            bw[mf] = *(const bf16x8*)(WoutT + (mf * 16 + l15) * 256 + h * 32 + lgrp * 8);
#pragma unroll
        for (int s = 0; s < 2; ++s) {
#pragma unroll
            for (int f = 0; f < 2; ++f) {
                const int ra = w * 32 + f * 16 + l15;
                const bf16x8 af = *(const bf16x8*)((const char*)g_lds + s * 8192 + ra * 64 + ((lgrp ^ (ra & 3)) * 16));
#pragma unroll
                for (int mf = 0; mf < 4; ++mf)
                    oacc[s][f][mf] = __builtin_amdgcn_mfma_f32_16x16x32_bf16(af, bw[mf], oacc[s][f][mf], 0, 0, 0);
            }
        }
        __syncthreads(); // g_lds consumed before next h overwrites
    }

    // store out: i on (lgrp, r), m on l15 (same pattern as old k4)
#pragma unroll
    for (int s = 0; s < 2; ++s)
#pragma unroll
        for (int f = 0; f < 2; ++f)
#pragma unroll
            for (int mf = 0; mf < 4; ++mf)
#pragma unroll
                for (int r = 0; r < 4; ++r) {
                    const size_t row = (size_t)(s0 + s) * 512 + i0 + w * 32 + f * 16 + lgrp * 4 + r;
                    out[row * 64 + mf * 16 + l15] = oacc[s][f][mf][r];
                }
}

extern "C" void kernel_launch(void* const* d_in, const int* in_sizes, int n_in,
                              void* d_out, int out_size, void* d_ws, size_t ws_size,
                              hipStream_t stream) {
    (void)in_sizes; (void)n_in; (void)out_size; (void)ws_size;
    const float* msa       = (const float*)d_in[0];
    const float* pair      = (const float*)d_in[1];
    const float* ln_msa_g  = (const float*)d_in[2];
    const float* ln_msa_b  = (const float*)d_in[3];
    const float* W_vg      = (const float*)d_in[4];
    const float* ln_pair_g = (const float*)d_in[5];
    const float* ln_pair_b = (const float*)d_in[6];
    const float* W_pair    = (const float*)d_in[7];
    const float* W_out     = (const float*)d_in[8];
    float* out = (float*)d_out;

    char* ws = (char*)d_ws;
    size_t off = 0;
    unsigned short* VT    = (unsigned short*)(ws + off); off += (size_t)ROWS * C * 2; // 67.1 MB
    unsigned short* G     = (unsigned short*)(ws + off); off += (size_t)ROWS * C * 2; // 67.1 MB
    unsigned short* Wt    = (unsigned short*)(ws + off); off += (size_t)H * N * N * 2; // 4.2 MB
    unsigned short* WTvg  = (unsigned short*)(ws + off); off += 512 * 64 * 2;          // 64 KB
    float*          biasvg = (float*)(ws + off); off += 512 * 4;                       // 2 KB
    unsigned short* WoutT = (unsigned short*)(ws + off); off += 64 * 256 * 2;          // 32 KB
    float*          Wg    = (float*)(ws + off); off += 128 * 8 * 4;                    // 4 KB
    float*          sgcb  = (float*)(ws + off); off += 16 * 4;

    k0_prep<<<4, 256, 0, stream>>>(W_vg, ln_msa_g, ln_msa_b, W_out, ln_pair_g, ln_pair_b, W_pair,
                                   WTvg, biasvg, WoutT, Wg, sgcb);
    k2_bias_softmax<<<512, 512, 0, stream>>>(pair, Wg, sgcb, Wt);
    k1_vg_mfma<<<512, 512, 0, stream>>>(msa, WTvg, biasvg, VT, G);
    k3_fused_out<<<512, 256, 0, stream>>>(Wt, VT, G, WoutT, out);
}